// Round 7
// baseline (929.817 us; speedup 1.0000x reference)
//
#include <hip/hip_runtime.h>
#include <hip/hip_bf16.h>
#include <cstdint>

#define H 1024
#define OSZ 32000
#define SLEN 16384

typedef __attribute__((ext_vector_type(8))) __bf16 bf16x8;
typedef __attribute__((ext_vector_type(4))) __bf16 bf16x4;
typedef __attribute__((ext_vector_type(4))) float f32x4;

// ---- fused: fp32->bf16 convert (enc + W_fc_encoder) ++ t1 = W_fc_hidden @ h0 ----
// blocks [0,2048): grid-stride convert; blocks [2048,2304): wave-per-row matvec.
__global__ __launch_bounds__(256) void convert_t1_kernel(
    const float* __restrict__ enc, const float* __restrict__ wfc,
    __bf16* __restrict__ outb,
    const float* __restrict__ Wfh, const float* __restrict__ h0,
    float* __restrict__ t1) {
  if (blockIdx.x < 2048) {
    const int ENC4 = SLEN * H / 4;
    const int TOT4 = ENC4 + H * H / 4;
    const int stride = 2048 * 256;
    for (int i = blockIdx.x * 256 + threadIdx.x; i < TOT4; i += stride) {
      float4 v = (i < ENC4) ? ((const float4*)enc)[i] : ((const float4*)wfc)[i - ENC4];
      bf16x4 b;
      b[0] = (__bf16)v.x; b[1] = (__bf16)v.y; b[2] = (__bf16)v.z; b[3] = (__bf16)v.w;
      ((bf16x4*)outb)[i] = b;
    }
  } else {
    int lane = threadIdx.x & 63, wid = threadIdx.x >> 6;
    int row = (blockIdx.x - 2048) * 4 + wid;
    const float4* Wr = (const float4*)(Wfh + (size_t)row * H);
    const float4* x4 = (const float4*)h0;
    float d = 0.f;
#pragma unroll
    for (int i = 0; i < 4; ++i) {
      float4 w = Wr[lane + 64 * i], x = x4[lane + 64 * i];
      d += w.x * x.x + w.y * x.y + w.z * x.z + w.w * x.w;
    }
#pragma unroll
    for (int off = 32; off; off >>= 1) d += __shfl_xor(d, off);
    if (lane == 0) t1[row] = d;
  }
}

// ---------------- attention GEMM: scores[s] += sum_h aw[h]*tanh(t1[h]+enc@Wfe^T) ----
// BM=BN=128, BK=64 bf16. global_load_lds(16B) with both-sides XOR swizzle
// (physical 16B slot = logical slot ^ (row&7) within each 128B row).
// Grid: blockIdx.x = bm (128, fast) so all 8 bn-blocks of a bm-panel land on
// the same XCD (linear%8 == bm%8) -> A-panel L2-resident.
__global__ __launch_bounds__(256, 2) void attn_gemm(
    const __bf16* __restrict__ A,   // enc bf16 [SLEN][H]
    const __bf16* __restrict__ B,   // W_fc_encoder bf16 [H][H] (row h = output col)
    const float* __restrict__ t1, const float* __restrict__ aw,
    float* __restrict__ scores) {
  __shared__ unsigned char smem[2 * 32768];  // [buf][A 16KB | B 16KB]
  const int tid = threadIdx.x;
  const int lane = tid & 63, wid = tid >> 6;
  const int bm = blockIdx.x, bn = blockIdx.y;
  const int wm = wid >> 1, wn = wid & 1;

  const int srow = lane >> 3;                   // staged row within 8-row group (= row&7)
  const int skoff = ((lane & 7) ^ srow) * 8;    // pre-swizzled global k-offset (elements)

  const __bf16* Ab = A + (size_t)(bm * 128) * H + skoff;
  const __bf16* Bb = B + (size_t)(bn * 128) * H + skoff;

  f32x4 acc[4][4];
#pragma unroll
  for (int i = 0; i < 4; ++i)
#pragma unroll
    for (int j = 0; j < 4; ++j) acc[i][j] = (f32x4)(0.f);

  auto stage = [&](int buf, int kt) {
    unsigned char* sa = smem + buf * 32768;
    unsigned char* sb = sa + 16384;
    const __bf16* ga0 = Ab + kt * 64;
    const __bf16* gb0 = Bb + kt * 64;
#pragma unroll
    for (int c = 0; c < 4; ++c) {
      int r = c * 32 + wid * 8 + srow;
      __builtin_amdgcn_global_load_lds(
          (const __attribute__((address_space(1))) void*)(ga0 + (size_t)r * H),
          (__attribute__((address_space(3))) void*)(sa + c * 4096 + wid * 1024), 16, 0, 0);
      __builtin_amdgcn_global_load_lds(
          (const __attribute__((address_space(1))) void*)(gb0 + (size_t)r * H),
          (__attribute__((address_space(3))) void*)(sb + c * 4096 + wid * 1024), 16, 0, 0);
    }
  };

  stage(0, 0);
  __syncthreads();
  for (int kt = 0; kt < 16; ++kt) {
    int cur = kt & 1;
    if (kt < 15) stage(cur ^ 1, kt + 1);
    const unsigned char* sa = smem + cur * 32768;
    const unsigned char* sb = sa + 16384;
#pragma unroll
    for (int kk = 0; kk < 2; ++kk) {
      bf16x8 af[4], bfr[4];
      const int kb = kk * 64 + (lane >> 4) * 16;  // logical byte-slot within 128B row
#pragma unroll
      for (int mi = 0; mi < 4; ++mi) {
        int r = wm * 64 + mi * 16 + (lane & 15);
        af[mi] = *(const bf16x8*)(sa + r * 128 + (kb ^ ((r & 7) << 4)));
      }
#pragma unroll
      for (int ni = 0; ni < 4; ++ni) {
        int r = wn * 64 + ni * 16 + (lane & 15);
        bfr[ni] = *(const bf16x8*)(sb + r * 128 + (kb ^ ((r & 7) << 4)));
      }
#pragma unroll
      for (int mi = 0; mi < 4; ++mi)
#pragma unroll
        for (int ni = 0; ni < 4; ++ni)
          acc[mi][ni] = __builtin_amdgcn_mfma_f32_16x16x32_bf16(af[mi], bfr[ni], acc[mi][ni], 0, 0, 0);
    }
    __syncthreads();
  }

  // fused epilogue: score[row] += sum_col aw[col]*tanh(t1[col]+u)
  float awv[4], t1v[4];
#pragma unroll
  for (int ni = 0; ni < 4; ++ni) {
    int col = bn * 128 + wn * 64 + ni * 16 + (lane & 15);
    awv[ni] = aw[col];
    t1v[ni] = t1[col];
  }
#pragma unroll
  for (int mi = 0; mi < 4; ++mi) {
#pragma unroll
    for (int e = 0; e < 4; ++e) {
      float s = 0.f;
#pragma unroll
      for (int ni = 0; ni < 4; ++ni)
        s += awv[ni] * tanhf(t1v[ni] + acc[mi][ni][e]);
      s += __shfl_xor(s, 1); s += __shfl_xor(s, 2);
      s += __shfl_xor(s, 4); s += __shfl_xor(s, 8);
      if ((lane & 15) == 0) {
        int grow = bm * 128 + wm * 64 + mi * 16 + (lane >> 4) * 4 + e;
        atomicAdd(&scores[grow], s);
      }
    }
  }
}

// ---------------- softmax over 16384 scores (single block) ----------------
__global__ __launch_bounds__(1024) void softmax_kernel(const float* __restrict__ scores,
                                                       float* __restrict__ attn) {
  __shared__ float red[16];
  int tid = threadIdx.x, lane = tid & 63, wid = tid >> 6;
  float v[16];
  float m = -1e30f;
#pragma unroll
  for (int i = 0; i < 16; ++i) { v[i] = scores[tid + 1024 * i]; m = fmaxf(m, v[i]); }
#pragma unroll
  for (int off = 32; off; off >>= 1) m = fmaxf(m, __shfl_xor(m, off));
  if (lane == 0) red[wid] = m;
  __syncthreads();
  float M = red[0];
#pragma unroll
  for (int i = 1; i < 16; ++i) M = fmaxf(M, red[i]);
  float lsum = 0.f;
#pragma unroll
  for (int i = 0; i < 16; ++i) { v[i] = expf(v[i] - M); lsum += v[i]; }
#pragma unroll
  for (int off = 32; off; off >>= 1) lsum += __shfl_xor(lsum, off);
  __syncthreads();
  if (lane == 0) red[wid] = lsum;
  __syncthreads();
  float T = 0.f;
#pragma unroll
  for (int i = 0; i < 16; ++i) T += red[i];
  float inv = 1.0f / T;
#pragma unroll
  for (int i = 0; i < 16; ++i) attn[tid + 1024 * i] = v[i] * inv;
}

// ------- context = attn @ enc (fp32 enc, full precision; 256 blocks x 64 rows) -------
__global__ __launch_bounds__(256) void context_kernel(const float* __restrict__ enc,
                                                      const float* __restrict__ attn,
                                                      float* __restrict__ ctx) {
  __shared__ float sa[64];
  int t = threadIdx.x;
  int s0 = blockIdx.x * 64;
  if (t < 64) sa[t] = attn[s0 + t];
  __syncthreads();
  const float4* base = (const float4*)enc + (size_t)s0 * (H / 4) + t;
  float a0 = 0, a1 = 0, a2 = 0, a3 = 0;
  for (int s = 0; s < 64; ++s) {
    float a = sa[s];
    float4 v = base[(size_t)s * (H / 4)];
    a0 += a * v.x; a1 += a * v.y; a2 += a * v.z; a3 += a * v.w;
  }
  atomicAdd(&ctx[4 * t + 0], a0); atomicAdd(&ctx[4 * t + 1], a1);
  atomicAdd(&ctx[4 * t + 2], a2); atomicAdd(&ctx[4 * t + 3], a3);
}

// ---------------- gates = W_ih @ [emb;ctx] + W_hh @ h0 + b (block per row) -------
__global__ __launch_bounds__(256) void gates_kernel(
    const float* __restrict__ Wih, const float* __restrict__ Whh,
    const float* __restrict__ emb, const float* __restrict__ ctx,
    const float* __restrict__ h0, const float* __restrict__ bih,
    const float* __restrict__ bhh, float* __restrict__ gates) {
  const int j = blockIdx.x;
  const int t = threadIdx.x;
  const float4* Wr = (const float4*)(Wih + (size_t)j * (OSZ + H));
  const float4* e4 = (const float4*)emb;
  const float4* c4 = (const float4*)ctx;
  float d = 0.f;
  for (int i = t; i < (OSZ + H) / 4; i += 256) {
    float4 w = Wr[i];
    float4 x = (i < OSZ / 4) ? e4[i] : c4[i - OSZ / 4];
    d += w.x * x.x + w.y * x.y + w.z * x.z + w.w * x.w;
  }
  const float4* Hr = (const float4*)(Whh + (size_t)j * H);
  const float4* h4 = (const float4*)h0;
  {
    float4 w = Hr[t], x = h4[t];
    d += w.x * x.x + w.y * x.y + w.z * x.z + w.w * x.w;
  }
  __shared__ float red[4];
#pragma unroll
  for (int off = 32; off; off >>= 1) d += __shfl_xor(d, off);
  int lane = t & 63, wid = t >> 6;
  if (lane == 0) red[wid] = d;
  __syncthreads();
  if (t == 0) gates[j] = red[0] + red[1] + red[2] + red[3] + bih[j] + bhh[j];
}

// ---------------- LSTM cell elementwise ----------------
__device__ __forceinline__ float sigf(float x) { return 1.0f / (1.0f + expf(-x)); }

__global__ void lstm_kernel(const float* __restrict__ gates, const float* __restrict__ c0,
                            float* __restrict__ h_out, float* __restrict__ c_out) {
  int k = blockIdx.x * blockDim.x + threadIdx.x;
  float ig = sigf(gates[k]);
  float fg = sigf(gates[k + H]);
  float gg = tanhf(gates[k + 2 * H]);
  float og = sigf(gates[k + 3 * H]);
  float c = fg * c0[k] + ig * gg;
  c_out[k] = c;
  h_out[k] = og * tanhf(c);
}

// ---------------- classifier: out = W_cls @ h_new + b (wave per row) ----------------
__global__ __launch_bounds__(256) void cls_kernel(const float* __restrict__ W,
                                                  const float* __restrict__ h,
                                                  const float* __restrict__ b,
                                                  float* __restrict__ out) {
  int lane = threadIdx.x & 63, wid = threadIdx.x >> 6;
  int row = blockIdx.x * 4 + wid;
  const float4* Wr = (const float4*)(W + (size_t)row * H);
  const float4* h4 = (const float4*)h;
  float d = 0.f;
#pragma unroll
  for (int i = 0; i < 4; ++i) {
    float4 w = Wr[lane + 64 * i], x = h4[lane + 64 * i];
    d += w.x * x.x + w.y * x.y + w.z * x.z + w.w * x.w;
  }
#pragma unroll
  for (int off = 32; off; off >>= 1) d += __shfl_xor(d, off);
  if (lane == 0) out[row] = d + b[row];
}

extern "C" void kernel_launch(void* const* d_in, const int* in_sizes, int n_in,
                              void* d_out, int out_size, void* d_ws, size_t ws_size,
                              hipStream_t stream) {
  (void)in_sizes; (void)n_in; (void)out_size; (void)ws_size;
  const float* inputs = (const float*)d_in[0];
  const float* h0   = (const float*)d_in[1];
  const float* c0   = (const float*)d_in[2];
  const float* enc  = (const float*)d_in[3];
  const float* Wfh  = (const float*)d_in[4];
  const float* Wfe  = (const float*)d_in[5];
  const float* aw   = (const float*)d_in[6];
  const float* Wih  = (const float*)d_in[7];
  const float* Whh  = (const float*)d_in[8];
  const float* bih  = (const float*)d_in[9];
  const float* bhh  = (const float*)d_in[10];
  const float* Wcls = (const float*)d_in[11];
  const float* bcls = (const float*)d_in[12];

  float* out = (float*)d_out;        // [32000] logits
  float* h_out = out + OSZ;          // [1024]
  float* c_out = h_out + H;          // [1024]
  float* attn_out = c_out + H;       // [16384]

  char* ws = (char*)d_ws;
  __bf16* enc_b = (__bf16*)ws;                       // 33,554,432 B
  __bf16* wfc_b = enc_b + (size_t)SLEN * H;          // 2,097,152 B
  float* t1  = (float*)(ws + 35651584);              // [1024]
  float* ctx = t1 + H;                               // [1024] (zeroed)
  float* scores = ctx + H;                           // [16384] (zeroed)
  float* gates = scores + SLEN;                      // [4096]

  hipMemsetAsync(ctx, 0, (H + SLEN) * sizeof(float), stream);
  convert_t1_kernel<<<2304, 256, 0, stream>>>(enc, Wfe, enc_b, Wfh, h0, t1);
  attn_gemm<<<dim3(128, 8), 256, 0, stream>>>(enc_b, wfc_b, t1, aw, scores);
  softmax_kernel<<<1, 1024, 0, stream>>>(scores, attn_out);
  context_kernel<<<SLEN / 64, 256, 0, stream>>>(enc, attn_out, ctx);
  gates_kernel<<<4 * H, 256, 0, stream>>>(Wih, Whh, inputs, ctx, h0, bih, bhh, gates);
  lstm_kernel<<<4, 256, 0, stream>>>(gates, c0, h_out, c_out);
  cls_kernel<<<OSZ / 4, 256, 0, stream>>>(Wcls, h_out, bcls, out);
}

// Round 8
// 925.984 us; speedup vs baseline: 1.0041x; 1.0041x over previous
//
#include <hip/hip_runtime.h>
#include <hip/hip_bf16.h>
#include <cstdint>

#define H 1024
#define OSZ 32000
#define SLEN 16384

typedef __attribute__((ext_vector_type(8))) __bf16 bf16x8;
typedef __attribute__((ext_vector_type(4))) __bf16 bf16x4;
typedef __attribute__((ext_vector_type(4))) float f32x4;

// ---- fused: fp32->bf16 convert (enc + W_fc_encoder) ++ t1 = W_fc_hidden @ h0 ----
__global__ __launch_bounds__(256) void convert_t1_kernel(
    const float* __restrict__ enc, const float* __restrict__ wfc,
    __bf16* __restrict__ outb,
    const float* __restrict__ Wfh, const float* __restrict__ h0,
    float* __restrict__ t1) {
  if (blockIdx.x < 2048) {
    const int ENC4 = SLEN * H / 4;
    const int TOT4 = ENC4 + H * H / 4;
    const int stride = 2048 * 256;
    for (int i = blockIdx.x * 256 + threadIdx.x; i < TOT4; i += stride) {
      float4 v = (i < ENC4) ? ((const float4*)enc)[i] : ((const float4*)wfc)[i - ENC4];
      bf16x4 b;
      b[0] = (__bf16)v.x; b[1] = (__bf16)v.y; b[2] = (__bf16)v.z; b[3] = (__bf16)v.w;
      ((bf16x4*)outb)[i] = b;
    }
  } else {
    int lane = threadIdx.x & 63, wid = threadIdx.x >> 6;
    int row = (blockIdx.x - 2048) * 4 + wid;
    const float4* Wr = (const float4*)(Wfh + (size_t)row * H);
    const float4* x4 = (const float4*)h0;
    float d = 0.f;
#pragma unroll
    for (int i = 0; i < 4; ++i) {
      float4 w = Wr[lane + 64 * i], x = x4[lane + 64 * i];
      d += w.x * x.x + w.y * x.y + w.z * x.z + w.w * x.w;
    }
#pragma unroll
    for (int off = 32; off; off >>= 1) d += __shfl_xor(d, off);
    if (lane == 0) t1[row] = d;
  }
}

// ---- mega kernel: attention GEMM (blocks 0..1023) ∥ gates-emb matvec (blocks 1024..2047) ----
// GEMM: BM=BN=128, BK=64 bf16, global_load_lds(16B), both-sides XOR swizzle,
// bm = bid%128 fast -> all 8 bn-panels of a bm share an XCD (L2-resident A).
// Gates-emb: wave-per-row streaming of W_ih[:, :32000] @ emb (524 MB) — fills the
// HBM bandwidth the MFMA-bound GEMM leaves idle (GEMM ~1.2 TB/s of 6.3).
__global__ __launch_bounds__(256, 2) void attn_gates_kernel(
    const __bf16* __restrict__ A,   // enc bf16 [SLEN][H]
    const __bf16* __restrict__ B,   // W_fc_encoder bf16 [H][H]
    const float* __restrict__ t1, const float* __restrict__ aw,
    float* __restrict__ scores,
    const float* __restrict__ Wih, const float* __restrict__ emb,
    float* __restrict__ gp) {
  if (blockIdx.x >= 1024) {
    // ---- gates-emb: row j = (bid-1024)*4 + wid; dot(W_ih[j, :32000], emb) ----
    int lane = threadIdx.x & 63, wid = threadIdx.x >> 6;
    int row = (blockIdx.x - 1024) * 4 + wid;
    const float4* Wr = (const float4*)(Wih + (size_t)row * (OSZ + H));
    const float4* e4 = (const float4*)emb;
    float d0 = 0.f, d1 = 0.f;
#pragma unroll 5
    for (int i = 0; i < 124; i += 2) {
      float4 w = Wr[lane + 64 * i], x = e4[lane + 64 * i];
      d0 += w.x * x.x + w.y * x.y + w.z * x.z + w.w * x.w;
      float4 w1 = Wr[lane + 64 * (i + 1)], x1 = e4[lane + 64 * (i + 1)];
      d1 += w1.x * x1.x + w1.y * x1.y + w1.z * x1.z + w1.w * x1.w;
    }
    {
      float4 w = Wr[lane + 64 * 124], x = e4[lane + 64 * 124];
      d0 += w.x * x.x + w.y * x.y + w.z * x.z + w.w * x.w;
    }
    float d = d0 + d1;
#pragma unroll
    for (int off = 32; off; off >>= 1) d += __shfl_xor(d, off);
    if (lane == 0) gp[row] = d;
    return;
  }

  // ---- attention GEMM path ----
  __shared__ unsigned char smem[2 * 32768];  // [buf][A 16KB | B 16KB]
  const int tid = threadIdx.x;
  const int lane = tid & 63, wid = tid >> 6;
  const int bm = blockIdx.x & 127, bn = blockIdx.x >> 7;
  const int wm = wid >> 1, wn = wid & 1;

  const int srow = lane >> 3;                   // staged row within 8-row group (= row&7)
  const int skoff = ((lane & 7) ^ srow) * 8;    // pre-swizzled global k-offset (elements)

  const __bf16* Ab = A + (size_t)(bm * 128) * H + skoff;
  const __bf16* Bb = B + (size_t)(bn * 128) * H + skoff;

  f32x4 acc[4][4];
#pragma unroll
  for (int i = 0; i < 4; ++i)
#pragma unroll
    for (int j = 0; j < 4; ++j) acc[i][j] = (f32x4)(0.f);

  auto stage = [&](int buf, int kt) {
    unsigned char* sa = smem + buf * 32768;
    unsigned char* sb = sa + 16384;
    const __bf16* ga0 = Ab + kt * 64;
    const __bf16* gb0 = Bb + kt * 64;
#pragma unroll
    for (int c = 0; c < 4; ++c) {
      int r = c * 32 + wid * 8 + srow;
      __builtin_amdgcn_global_load_lds(
          (const __attribute__((address_space(1))) void*)(ga0 + (size_t)r * H),
          (__attribute__((address_space(3))) void*)(sa + c * 4096 + wid * 1024), 16, 0, 0);
      __builtin_amdgcn_global_load_lds(
          (const __attribute__((address_space(1))) void*)(gb0 + (size_t)r * H),
          (__attribute__((address_space(3))) void*)(sb + c * 4096 + wid * 1024), 16, 0, 0);
    }
  };

  stage(0, 0);
  __syncthreads();
  for (int kt = 0; kt < 16; ++kt) {
    int cur = kt & 1;
    if (kt < 15) stage(cur ^ 1, kt + 1);
    const unsigned char* sa = smem + cur * 32768;
    const unsigned char* sb = sa + 16384;
#pragma unroll
    for (int kk = 0; kk < 2; ++kk) {
      bf16x8 af[4], bfr[4];
      const int kb = kk * 64 + (lane >> 4) * 16;  // logical byte-slot within 128B row
#pragma unroll
      for (int mi = 0; mi < 4; ++mi) {
        int r = wm * 64 + mi * 16 + (lane & 15);
        af[mi] = *(const bf16x8*)(sa + r * 128 + (kb ^ ((r & 7) << 4)));
      }
#pragma unroll
      for (int ni = 0; ni < 4; ++ni) {
        int r = wn * 64 + ni * 16 + (lane & 15);
        bfr[ni] = *(const bf16x8*)(sb + r * 128 + (kb ^ ((r & 7) << 4)));
      }
#pragma unroll
      for (int mi = 0; mi < 4; ++mi)
#pragma unroll
        for (int ni = 0; ni < 4; ++ni)
          acc[mi][ni] = __builtin_amdgcn_mfma_f32_16x16x32_bf16(af[mi], bfr[ni], acc[mi][ni], 0, 0, 0);
    }
    __syncthreads();
  }

  // fused epilogue: score[row] += sum_col aw[col]*tanh(t1[col]+u)
  float awv[4], t1v[4];
#pragma unroll
  for (int ni = 0; ni < 4; ++ni) {
    int col = bn * 128 + wn * 64 + ni * 16 + (lane & 15);
    awv[ni] = aw[col];
    t1v[ni] = t1[col];
  }
#pragma unroll
  for (int mi = 0; mi < 4; ++mi) {
#pragma unroll
    for (int e = 0; e < 4; ++e) {
      float s = 0.f;
#pragma unroll
      for (int ni = 0; ni < 4; ++ni)
        s += awv[ni] * tanhf(t1v[ni] + acc[mi][ni][e]);
      s += __shfl_xor(s, 1); s += __shfl_xor(s, 2);
      s += __shfl_xor(s, 4); s += __shfl_xor(s, 8);
      if ((lane & 15) == 0) {
        int grow = bm * 128 + wm * 64 + mi * 16 + (lane >> 4) * 4 + e;
        atomicAdd(&scores[grow], s);
      }
    }
  }
}

// ---------------- softmax over 16384 scores (single block) ----------------
__global__ __launch_bounds__(1024) void softmax_kernel(const float* __restrict__ scores,
                                                       float* __restrict__ attn) {
  __shared__ float red[16];
  int tid = threadIdx.x, lane = tid & 63, wid = tid >> 6;
  float v[16];
  float m = -1e30f;
#pragma unroll
  for (int i = 0; i < 16; ++i) { v[i] = scores[tid + 1024 * i]; m = fmaxf(m, v[i]); }
#pragma unroll
  for (int off = 32; off; off >>= 1) m = fmaxf(m, __shfl_xor(m, off));
  if (lane == 0) red[wid] = m;
  __syncthreads();
  float M = red[0];
#pragma unroll
  for (int i = 1; i < 16; ++i) M = fmaxf(M, red[i]);
  float lsum = 0.f;
#pragma unroll
  for (int i = 0; i < 16; ++i) { v[i] = expf(v[i] - M); lsum += v[i]; }
#pragma unroll
  for (int off = 32; off; off >>= 1) lsum += __shfl_xor(lsum, off);
  __syncthreads();
  if (lane == 0) red[wid] = lsum;
  __syncthreads();
  float T = 0.f;
#pragma unroll
  for (int i = 0; i < 16; ++i) T += red[i];
  float inv = 1.0f / T;
#pragma unroll
  for (int i = 0; i < 16; ++i) attn[tid + 1024 * i] = v[i] * inv;
}

// ------- context = attn @ enc (fp32 enc, full precision; 256 blocks x 64 rows) -------
__global__ __launch_bounds__(256) void context_kernel(const float* __restrict__ enc,
                                                      const float* __restrict__ attn,
                                                      float* __restrict__ ctx) {
  __shared__ float sa[64];
  int t = threadIdx.x;
  int s0 = blockIdx.x * 64;
  if (t < 64) sa[t] = attn[s0 + t];
  __syncthreads();
  const float4* base = (const float4*)enc + (size_t)s0 * (H / 4) + t;
  float a0 = 0, a1 = 0, a2 = 0, a3 = 0;
  for (int s = 0; s < 64; ++s) {
    float a = sa[s];
    float4 v = base[(size_t)s * (H / 4)];
    a0 += a * v.x; a1 += a * v.y; a2 += a * v.z; a3 += a * v.w;
  }
  atomicAdd(&ctx[4 * t + 0], a0); atomicAdd(&ctx[4 * t + 1], a1);
  atomicAdd(&ctx[4 * t + 2], a2); atomicAdd(&ctx[4 * t + 3], a3);
}

// ---- gates_finish: gates[j] = gp[j] + W_ih[j,OSZ:]@ctx + W_hh[j]@h0 + b_ih + b_hh ----
__global__ __launch_bounds__(256) void gates_finish_kernel(
    const float* __restrict__ Wih, const float* __restrict__ Whh,
    const float* __restrict__ ctx, const float* __restrict__ h0,
    const float* __restrict__ bih, const float* __restrict__ bhh,
    const float* __restrict__ gp, float* __restrict__ gates) {
  int lane = threadIdx.x & 63, wid = threadIdx.x >> 6;
  int j = blockIdx.x * 4 + wid;
  const float4* Wc = (const float4*)(Wih + (size_t)j * (OSZ + H) + OSZ);
  const float4* c4 = (const float4*)ctx;
  const float4* Hr = (const float4*)(Whh + (size_t)j * H);
  const float4* h4 = (const float4*)h0;
  float d = 0.f;
#pragma unroll
  for (int i = 0; i < 4; ++i) {
    float4 w = Wc[lane + 64 * i], x = c4[lane + 64 * i];
    d += w.x * x.x + w.y * x.y + w.z * x.z + w.w * x.w;
    float4 wh = Hr[lane + 64 * i], xh = h4[lane + 64 * i];
    d += wh.x * xh.x + wh.y * xh.y + wh.z * xh.z + wh.w * xh.w;
  }
#pragma unroll
  for (int off = 32; off; off >>= 1) d += __shfl_xor(d, off);
  if (lane == 0) gates[j] = d + gp[j] + bih[j] + bhh[j];
}

// ---------------- LSTM cell elementwise ----------------
__device__ __forceinline__ float sigf(float x) { return 1.0f / (1.0f + expf(-x)); }

__global__ void lstm_kernel(const float* __restrict__ gates, const float* __restrict__ c0,
                            float* __restrict__ h_out, float* __restrict__ c_out) {
  int k = blockIdx.x * blockDim.x + threadIdx.x;
  float ig = sigf(gates[k]);
  float fg = sigf(gates[k + H]);
  float gg = tanhf(gates[k + 2 * H]);
  float og = sigf(gates[k + 3 * H]);
  float c = fg * c0[k] + ig * gg;
  c_out[k] = c;
  h_out[k] = og * tanhf(c);
}

// ---------------- classifier: out = W_cls @ h_new + b (wave per row) ----------------
__global__ __launch_bounds__(256) void cls_kernel(const float* __restrict__ W,
                                                  const float* __restrict__ h,
                                                  const float* __restrict__ b,
                                                  float* __restrict__ out) {
  int lane = threadIdx.x & 63, wid = threadIdx.x >> 6;
  int row = blockIdx.x * 4 + wid;
  const float4* Wr = (const float4*)(W + (size_t)row * H);
  const float4* h4 = (const float4*)h;
  float d = 0.f;
#pragma unroll
  for (int i = 0; i < 4; ++i) {
    float4 w = Wr[lane + 64 * i], x = h4[lane + 64 * i];
    d += w.x * x.x + w.y * x.y + w.z * x.z + w.w * x.w;
  }
#pragma unroll
  for (int off = 32; off; off >>= 1) d += __shfl_xor(d, off);
  if (lane == 0) out[row] = d + b[row];
}

extern "C" void kernel_launch(void* const* d_in, const int* in_sizes, int n_in,
                              void* d_out, int out_size, void* d_ws, size_t ws_size,
                              hipStream_t stream) {
  (void)in_sizes; (void)n_in; (void)out_size; (void)ws_size;
  const float* inputs = (const float*)d_in[0];
  const float* h0   = (const float*)d_in[1];
  const float* c0   = (const float*)d_in[2];
  const float* enc  = (const float*)d_in[3];
  const float* Wfh  = (const float*)d_in[4];
  const float* Wfe  = (const float*)d_in[5];
  const float* aw   = (const float*)d_in[6];
  const float* Wih  = (const float*)d_in[7];
  const float* Whh  = (const float*)d_in[8];
  const float* bih  = (const float*)d_in[9];
  const float* bhh  = (const float*)d_in[10];
  const float* Wcls = (const float*)d_in[11];
  const float* bcls = (const float*)d_in[12];

  float* out = (float*)d_out;        // [32000] logits
  float* h_out = out + OSZ;          // [1024]
  float* c_out = h_out + H;          // [1024]
  float* attn_out = c_out + H;       // [16384]

  char* ws = (char*)d_ws;
  __bf16* enc_b = (__bf16*)ws;                       // 33,554,432 B
  __bf16* wfc_b = enc_b + (size_t)SLEN * H;          // 2,097,152 B
  float* t1  = (float*)(ws + 35651584);              // [1024]
  float* ctx = t1 + H;                               // [1024] (zeroed)
  float* scores = ctx + H;                           // [16384] (zeroed)
  float* gates = scores + SLEN;                      // [4096]
  float* gp = gates + 4 * H;                         // [4096] gates-emb partial

  hipMemsetAsync(ctx, 0, (H + SLEN) * sizeof(float), stream);
  convert_t1_kernel<<<2304, 256, 0, stream>>>(enc, Wfe, enc_b, Wfh, h0, t1);
  attn_gates_kernel<<<2048, 256, 0, stream>>>(enc_b, wfc_b, t1, aw, scores,
                                              Wih, inputs, gp);
  softmax_kernel<<<1, 1024, 0, stream>>>(scores, attn_out);
  context_kernel<<<SLEN / 64, 256, 0, stream>>>(enc, attn_out, ctx);
  gates_finish_kernel<<<H, 256, 0, stream>>>(Wih, Whh, ctx, h0, bih, bhh, gp, gates);
  lstm_kernel<<<4, 256, 0, stream>>>(gates, c0, h_out, c_out);
  cls_kernel<<<OSZ / 4, 256, 0, stream>>>(Wcls, h_out, bcls, out);
}